// Round 25
// baseline (90.796 us; speedup 1.0000x reference)
//
#include <hip/hip_runtime.h>
#include <math.h>

// Problem constants (CapsNet routing)
#define BB   256   // batch
#define NI   1152  // input capsules
#define DI   8     // input dim
#define NJ   10    // output capsules
#define DJ   16    // output dim
#define NCHUNK 18  // NI / CHUNK
#define CHUNK  64  // i per block
#define BG     32  // batch per A0m block
#define NBG    8   // BB / BG
#define GRID_MAIN (NJ * NCHUNK * NBG)   // 1440 = 8 XCD x 180
#define BG2   8    // batch per BSA block
#define GRID_BSA (8 * NCHUNK * (32 / BG2))  // 576 = 8 XCD x 72
#define CTP2 68    // ctile row pad (f16)

typedef _Float16 half2_t __attribute__((ext_vector_type(2)));
typedef _Float16 half4_t __attribute__((ext_vector_type(4)));
typedef _Float16 half8_t __attribute__((ext_vector_type(8)));
typedef float    f32x4   __attribute__((ext_vector_type(4)));

// DPP cross-lane adds (VALU pipe)
// 0x0B1 quad_perm lane^1, 0x04E quad_perm lane^2
template <int CTRL>
__device__ __forceinline__ float dpp_add(float x) {
    int xi = __float_as_int(x);
    int yi = __builtin_amdgcn_update_dpp(0, xi, CTRL, 0xF, 0xF, true);
    return x + __int_as_float(yi);
}

// f16 dot-8 with f32 accumulation: 4 chained v_dot2_f32_f16
__device__ __forceinline__ float dot16(half8_t w, half8_t uu) {
    half2_t w0 = {w[0], w[1]}, w1 = {w[2], w[3]}, w2 = {w[4], w[5]}, w3 = {w[6], w[7]};
    half2_t a0 = {uu[0], uu[1]}, a1 = {uu[2], uu[3]}, a2 = {uu[4], uu[5]}, a3 = {uu[6], uu[7]};
    float acc = __builtin_amdgcn_fdot2(w0, a0, 0.f, false);
    acc = __builtin_amdgcn_fdot2(w1, a1, acc, false);
    acc = __builtin_amdgcn_fdot2(w2, a2, acc, false);
    acc = __builtin_amdgcn_fdot2(w3, a3, acc, false);
    return acc;
}

struct Ctx {
    int j, chunk, bg, i0, b0, tid, il, dq, lane, w, g, xcd, local;
};

// A0m swizzle (proven): xcd owns bg == xcd, all (j,chunk)
__device__ __forceinline__ Ctx make_ctx(int bid, int tid) {
    Ctx c;
    c.xcd = bid & 7; c.local = bid >> 3;
    int gx = c.xcd * (GRID_MAIN / 8) + c.local;
    c.j = gx % NJ; int r = gx / NJ;
    c.chunk = r % NCHUNK; c.bg = r / NCHUNK;
    c.i0 = c.chunk * CHUNK; c.b0 = c.bg * BG;
    c.tid = tid; c.il = tid >> 2; c.dq = tid & 3;
    c.lane = tid & 63; c.w = tid >> 6; c.g = (c.lane >> 4) & 3;
    return c;
}

// MFMA-layout W fragment
__device__ __forceinline__ void loadWf(const _Float16* __restrict__ W16, const Ctx& cx,
                                       half8_t* Wf) {
    int drow = cx.lane & 15, ksub = cx.lane >> 4;
#pragma unroll
    for (int qq = 0; qq < 4; ++qq) {
        int i = cx.i0 + cx.w * 16 + qq * 4 + ksub;
        Wf[qq] = *(const half8_t*)(W16 + (((size_t)cx.j * NI + i) * DJ + drow) * DI);
    }
}

// ---- f32 -> f16 conversion, 4 float4 per thread (grid 936) ----
__global__ __launch_bounds__(256) void k_cvt(const float* __restrict__ uf,
                                             const float* __restrict__ Wf,
                                             _Float16* __restrict__ u16,
                                             _Float16* __restrict__ W16) {
    const int nu4 = (BB * NI * DI) / 4;
    int base = (blockIdx.x * 256 + threadIdx.x) * 4;
    if (base < nu4) {
#pragma unroll
        for (int t = 0; t < 4; ++t) {
            float4 v = ((const float4*)uf)[base + t];
            half4_t h = {(_Float16)v.x, (_Float16)v.y, (_Float16)v.z, (_Float16)v.w};
            ((half4_t*)u16)[base + t] = h;
        }
    } else {
        int k = base - nu4;
#pragma unroll
        for (int t = 0; t < 4; ++t) {
            float4 v = ((const float4*)Wf)[k + t];
            half4_t h = {(_Float16)v.x, (_Float16)v.y, (_Float16)v.z, (_Float16)v.w};
            ((half4_t*)W16)[k + t] = h;
        }
    }
}

// ---- k_A0m: iter-0 A phase, MFMA, c=0.1 exact; split accumulators ----
__global__ __launch_bounds__(256) void k_A0m(const _Float16* __restrict__ u16,
                                             const _Float16* __restrict__ W16,
                                             float* __restrict__ spart) {
    __shared__ __align__(16) float sres2[2 * 4 * 16 * 17];
    Ctx cx = make_ctx(blockIdx.x, threadIdx.x);
    half8_t Wf[4];
    loadWf(W16, cx, Wf);
    int l = cx.lane, w = cx.w;
    int drow = l & 15, ksub = l >> 4;

    half8_t au[2][4];
#pragma unroll
    for (int h = 0; h < 2; ++h) {
        int b = cx.b0 + h * 16 + drow;
#pragma unroll
        for (int qq = 0; qq < 4; ++qq) {
            int il = w * 16 + qq * 4 + ksub;
            au[h][qq] = *(const half8_t*)(u16 + ((size_t)b * NI + cx.i0 + il) * DI);
        }
    }
#pragma unroll
    for (int h = 0; h < 2; ++h) {
        f32x4 acc0 = {0.f, 0.f, 0.f, 0.f};
        f32x4 acc1 = {0.f, 0.f, 0.f, 0.f};
        acc0 = __builtin_amdgcn_mfma_f32_16x16x32_f16(au[h][0], Wf[0], acc0, 0, 0, 0);
        acc1 = __builtin_amdgcn_mfma_f32_16x16x32_f16(au[h][1], Wf[1], acc1, 0, 0, 0);
        acc0 = __builtin_amdgcn_mfma_f32_16x16x32_f16(au[h][2], Wf[2], acc0, 0, 0, 0);
        acc1 = __builtin_amdgcn_mfma_f32_16x16x32_f16(au[h][3], Wf[3], acc1, 0, 0, 0);
        f32x4 acc = acc0 + acc1;
#pragma unroll
        for (int r = 0; r < 4; ++r)
            sres2[((h * 4 + w) * 16 + ksub * 4 + r) * 17 + drow] = acc[r];
    }
    __syncthreads();
#pragma unroll
    for (int p = 0; p < 2; ++p) {
        int idx = p * 256 + cx.tid;
        int d = idx & 15, brow = (idx >> 4) & 15, h = idx >> 8;
        float s = 0.f;
#pragma unroll
        for (int w2 = 0; w2 < 4; ++w2)
            s += sres2[((h * 4 + w2) * 16 + brow) * 17 + d];
        s *= 0.1f;
        spart[(((size_t)cx.chunk * BB + cx.b0 + h * 16 + brow) * NJ + cx.j) * DJ + d] = s;
    }
}

// ---- k_BSA: fused {squash -> B -> softmax -> A}; 512 threads, j split
// across two 256-thread halves (jh = tid>>8, j = 2*it + jh): j-loops run 5
// iterations. PING-PONG spart: reads sin, writes sout (fixes the cross-block
// WAR race present in rounds 18-24: phase 1 reads ALL chunks while phase 4
// writes this block's chunk -- same-buffer = dispatch-timing dependent).
// ITER=0: v = v1; chunk==0 blocks persist v1 to vbuf.
// ITER=1: v = v1 + vbuf (= v0+v1): B phase produces TOTAL delta in LDS.
template <int ITER>
__global__ __launch_bounds__(512) void k_BSA(const _Float16* __restrict__ u16,
                                             const _Float16* __restrict__ W16,
                                             const float* __restrict__ sin,
                                             float* __restrict__ sout,
                                             float* __restrict__ vbuf) {
    __shared__ __align__(16) float     vsm[BG2 * NJ * DJ];        // 5120 B
    __shared__ __align__(16) _Float16  dtile[BG2 * NJ * CHUNK];   // 10240 B
    __shared__ __align__(16) _Float16  ctile[NJ * BG2 * CTP2];    // 10880 B
    __shared__ __align__(16) float     sres[NJ * 4 * BG2 * 17];   // 21760 B

    int xcd = blockIdx.x & 7, local = blockIdx.x >> 3;   // local 0..71
    int chunk = local % NCHUNK;
    int bgl   = local / NCHUNK;                          // 0..3
    int b0 = xcd * 32 + bgl * BG2;
    int i0 = chunk * CHUNK;
    int tid = threadIdx.x;
    int jh = tid >> 8;                                   // j-half 0/1
    int half_tid = tid & 255;
    int lane = tid & 63, w = (tid >> 6) & 3;             // wave within half
    int il = half_tid >> 2, dq = tid & 3;
    int drow = lane & 15, ksub = lane >> 4;
    bool brow_ok = drow < BG2;

    // ---- early u-loads (latency hides under squash) ----
    half8_t pu[BG2];                                     // phase-2 layout
#pragma unroll
    for (int b8 = 0; b8 < BG2; ++b8)
        pu[b8] = *(const half8_t*)(u16 + ((size_t)(b0 + b8) * NI + i0 + il) * DI);
    half8_t au0[4];                                      // phase-4 layout
#pragma unroll
    for (int qq = 0; qq < 4; ++qq) {
        int ili = w * 16 + qq * 4 + ksub;
        au0[qq] = brow_ok
            ? *(const half8_t*)(u16 + ((size_t)(b0 + drow) * NI + i0 + ili) * DI)
            : (half8_t){0, 0, 0, 0, 0, 0, 0, 0};
    }
    // pre-issue phase-2 W fragments for it=0,1 (j = jh, jh+2)
    half8_t Wh[3][4];
#pragma unroll
    for (int it = 0; it < 2; ++it) {
        int j = it * 2 + jh;
        const half8_t* wp = (const half8_t*)(W16 +
            (((size_t)j * NI + i0 + il) * DJ + dq * 4) * DI);
#pragma unroll
        for (int q = 0; q < 4; ++q) Wh[it][q] = wp[q];
    }

    // ---- phase 1: v1 = squash(sum_ch sin); vtot per ITER; 320 slots ----
    {
        int slot = tid;
        if (slot < BG2 * NJ * 4) {                       // 320 (40 per b8; 40%4==0)
            int b8 = slot / 40, rem = slot - b8 * 40;
            int j = rem >> 2, dq2 = rem & 3;
            int b = b0 + b8;
            float4 s4 = {0.f, 0.f, 0.f, 0.f};
#pragma unroll
            for (int ch = 0; ch < NCHUNK; ++ch) {
                float4 t = *(const float4*)&sin[(((size_t)ch * BB + b) * NJ + j) * DJ + dq2 * 4];
                s4.x += t.x; s4.y += t.y; s4.z += t.z; s4.w += t.w;
            }
            float sq = s4.x * s4.x + s4.y * s4.y + s4.z * s4.z + s4.w * s4.w;
            sq = dpp_add<0x0B1>(sq);   // quads align with dq2
            sq = dpp_add<0x04E>(sq);
            float scale = (sq / (1.f + sq)) / sqrtf(sq + 1e-7f);
            float4 vv; vv.x = s4.x * scale; vv.y = s4.y * scale;
            vv.z = s4.z * scale; vv.w = s4.w * scale;
            size_t va = ((size_t)b * NJ + j) * DJ + dq2 * 4;
            if (ITER == 0) {
                if (chunk == 0) *(float4*)&vbuf[va] = vv;   // persist v0
            } else {
                float4 v0 = *(const float4*)&vbuf[va];      // vtot = v0 + v1
                vv.x += v0.x; vv.y += v0.y; vv.z += v0.z; vv.w += v0.w;
            }
            *(float4*)&vsm[(b8 * NJ + j) * DJ + dq2 * 4] = vv;
        }
    }
    __syncthreads();

    // ---- phase 2: B, 5 iterations (j = 2*it + jh); depth-2 prefetch ----
#pragma unroll
    for (int it = 0; it < 5; ++it) {
        int j = it * 2 + jh;
        if (it + 2 < 5) {
            const half8_t* wp = (const half8_t*)(W16 +
                (((size_t)(j + 4) * NI + i0 + il) * DJ + dq * 4) * DI);
#pragma unroll
            for (int q = 0; q < 4; ++q) Wh[(it + 2) % 3][q] = wp[q];
        }
        float pj[BG2];
#pragma unroll
        for (int b8 = 0; b8 < BG2; ++b8) {
            float4 vv = *(const float4*)&vsm[(b8 * NJ + j) * DJ + dq * 4];
            float p = vv.x * dot16(Wh[it % 3][0], pu[b8]);
            p = fmaf(vv.y, dot16(Wh[it % 3][1], pu[b8]), p);
            p = fmaf(vv.z, dot16(Wh[it % 3][2], pu[b8]), p);
            p = fmaf(vv.w, dot16(Wh[it % 3][3], pu[b8]), p);
            p = dpp_add<0x0B1>(p);
            p = dpp_add<0x04E>(p);
            pj[b8] = p;
        }
        if (dq == 0) {
#pragma unroll
            for (int b8 = 0; b8 < BG2; ++b8)
                dtile[(b8 * NJ + j) * CHUNK + il] = (_Float16)pj[b8];
        }
    }

    // pre-issue phase-4 W fragments for it=0,1 (hide under barrier + softmax)
    half8_t Wf[3][4];
#pragma unroll
    for (int it = 0; it < 2; ++it) {
        int j = it * 2 + jh;
#pragma unroll
        for (int qq = 0; qq < 4; ++qq) {
            int i = i0 + w * 16 + qq * 4 + ksub;
            Wf[it][qq] = *(const half8_t*)(W16 + (((size_t)j * NI + i) * DJ + drow) * DI);
        }
    }
    __syncthreads();

    // ---- phase 3: softmax over j from dtile -> ctile (f16; no max-sub,
    //      |delta| <= ~12 analytically: f32-exp safe); 512 pairs, 1 pass ----
    {
        int b8 = tid >> 6, i = tid & 63;
        float x[NJ]; float ssum = 0.f;
#pragma unroll
        for (int j = 0; j < NJ; ++j) {
            x[j] = __expf((float)dtile[(b8 * NJ + j) * CHUNK + i]);
            ssum += x[j];
        }
        float rs = 1.f / ssum;
#pragma unroll
        for (int j = 0; j < NJ; ++j)
            ctile[(j * BG2 + b8) * CTP2 + i] = (_Float16)(x[j] * rs);
    }
    __syncthreads();

    // ---- phase 4: MFMA A, 5 iterations (j = 2*it + jh); depth-2 prefetch;
    //      split accumulators ----
#pragma unroll
    for (int it = 0; it < 5; ++it) {
        int j = it * 2 + jh;
        if (it + 2 < 5) {
#pragma unroll
            for (int qq = 0; qq < 4; ++qq) {
                int i = i0 + w * 16 + qq * 4 + ksub;
                Wf[(it + 2) % 3][qq] =
                    *(const half8_t*)(W16 + (((size_t)(j + 4) * NI + i) * DJ + drow) * DI);
            }
        }
        half8_t av[4];
#pragma unroll
        for (int qq = 0; qq < 4; ++qq) {
            int ili = w * 16 + qq * 4 + ksub;
            _Float16 ch = brow_ok ? ctile[(j * BG2 + drow) * CTP2 + ili] : (_Float16)0.f;
            half8_t cc = {ch, ch, ch, ch, ch, ch, ch, ch};
            av[qq] = au0[qq] * cc;
        }
        f32x4 acc0 = {0.f, 0.f, 0.f, 0.f};
        f32x4 acc1 = {0.f, 0.f, 0.f, 0.f};
        acc0 = __builtin_amdgcn_mfma_f32_16x16x32_f16(av[0], Wf[it % 3][0], acc0, 0, 0, 0);
        acc1 = __builtin_amdgcn_mfma_f32_16x16x32_f16(av[1], Wf[it % 3][1], acc1, 0, 0, 0);
        acc0 = __builtin_amdgcn_mfma_f32_16x16x32_f16(av[2], Wf[it % 3][2], acc0, 0, 0, 0);
        acc1 = __builtin_amdgcn_mfma_f32_16x16x32_f16(av[3], Wf[it % 3][3], acc1, 0, 0, 0);
        f32x4 acc = acc0 + acc1;
        if (ksub < 2) {                                  // output rows 0..7
#pragma unroll
            for (int r = 0; r < 4; ++r)
                sres[((j * 4 + w) * BG2 + ksub * 4 + r) * 17 + drow] = acc[r];
        }
    }
    __syncthreads();
    // epilogue: 1280 outputs (j 10 x brow 8 x d 16), 3 guarded passes
#pragma unroll
    for (int p = 0; p < 3; ++p) {
        int idx = p * 512 + tid;
        if (idx < NJ * BG2 * DJ) {
            int d = idx & 15, brow2 = (idx >> 4) & 7, j = idx >> 7;
            float s = 0.f;
#pragma unroll
            for (int w2 = 0; w2 < 4; ++w2)
                s += sres[((j * 4 + w2) * BG2 + brow2) * 17 + d];
            sout[(((size_t)chunk * BB + b0 + brow2) * NJ + j) * DJ + d] = s;
        }
    }
}

// ---- k_V: out = squash(sum_ch spart), vectorized: 40 blocks x 256 ----
__global__ __launch_bounds__(256) void k_V(const float* __restrict__ spart,
                                           float* __restrict__ out) {
    int idx4 = blockIdx.x * 256 + threadIdx.x;
    float4 s4 = {0.f, 0.f, 0.f, 0.f};
#pragma unroll
    for (int ch = 0; ch < NCHUNK; ++ch) {
        float4 t = *(const float4*)&spart[(size_t)ch * (BB * NJ * DJ) + (size_t)idx4 * 4];
        s4.x += t.x; s4.y += t.y; s4.z += t.z; s4.w += t.w;
    }
    float sq = s4.x * s4.x + s4.y * s4.y + s4.z * s4.z + s4.w * s4.w;
    sq = dpp_add<0x0B1>(sq);
    sq = dpp_add<0x04E>(sq);
    float scale = (sq / (1.f + sq)) / sqrtf(sq + 1e-7f);
    float4 o; o.x = s4.x * scale; o.y = s4.y * scale;
    o.z = s4.z * scale; o.w = s4.w * scale;
    *(float4*)&out[(size_t)idx4 * 4] = o;
}

extern "C" void kernel_launch(void* const* d_in, const int* in_sizes, int n_in,
                              void* d_out, int out_size, void* d_ws, size_t ws_size,
                              hipStream_t stream) {
    const float* u = (const float*)d_in[0];   // (256,1152,8)
    const float* W = (const float*)d_in[1];   // (10,1152,16,8)
    float* out = (float*)d_out;               // (256,10,16)

    const size_t SPART_N = (size_t)NCHUNK * BB * NJ * DJ;         // 737280
    float*     spartA = (float*)d_ws;
    float*     spartB = spartA + SPART_N;
    float*     vbuf   = spartB + SPART_N;                         // BB*NJ*DJ f32
    _Float16*  u16    = (_Float16*)(vbuf + (size_t)BB * NJ * DJ);
    _Float16*  W16    = u16 + (size_t)BB * NI * DI;

    dim3 blk(256);
    const int GRID_CVT = ((BB * NI * DI) / 4 + (NJ * NI * DJ * DI) / 4) / (256 * 4);  // 936

    // 5 launches: cvt -> A0m(A) -> BSA0(A->B) -> BSA1(B->A) -> V(A)
    k_cvt<<<GRID_CVT, blk, 0, stream>>>(u, W, u16, W16);
    k_A0m<<<GRID_MAIN, blk, 0, stream>>>(u16, W16, spartA);
    k_BSA<0><<<GRID_BSA, dim3(512), 0, stream>>>(u16, W16, spartA, spartB, vbuf);
    k_BSA<1><<<GRID_BSA, dim3(512), 0, stream>>>(u16, W16, spartB, spartA, vbuf);
    k_V<<<40, blk, 0, stream>>>(spartA, out);
}

// Round 26
// 73.168 us; speedup vs baseline: 1.2409x; 1.2409x over previous
//
#include <hip/hip_runtime.h>
#include <math.h>

// Problem constants (CapsNet routing)
#define BB   256   // batch
#define NI   1152  // input capsules
#define DI   8     // input dim
#define NJ   10    // output capsules
#define DJ   16    // output dim
#define NCHUNK 18  // NI / CHUNK
#define CHUNK  64  // i per block
#define BG     32  // batch per A0m block
#define NBG    8   // BB / BG
#define GRID_MAIN (NJ * NCHUNK * NBG)   // 1440 = 8 XCD x 180
#define BG2   8    // batch per BSA block (BG2=4 and 512-thread j-split both regressed)
#define GRID_BSA (8 * NCHUNK * (32 / BG2))  // 576 = 8 XCD x 72
#define CTP2 68    // ctile row pad (f16)

typedef _Float16 half2_t __attribute__((ext_vector_type(2)));
typedef _Float16 half4_t __attribute__((ext_vector_type(4)));
typedef _Float16 half8_t __attribute__((ext_vector_type(8)));
typedef float    f32x4   __attribute__((ext_vector_type(4)));

// DPP cross-lane adds (VALU pipe)
// 0x0B1 quad_perm lane^1, 0x04E quad_perm lane^2
template <int CTRL>
__device__ __forceinline__ float dpp_add(float x) {
    int xi = __float_as_int(x);
    int yi = __builtin_amdgcn_update_dpp(0, xi, CTRL, 0xF, 0xF, true);
    return x + __int_as_float(yi);
}

// f16 dot-8 with f32 accumulation: 4 chained v_dot2_f32_f16
__device__ __forceinline__ float dot16(half8_t w, half8_t uu) {
    half2_t w0 = {w[0], w[1]}, w1 = {w[2], w[3]}, w2 = {w[4], w[5]}, w3 = {w[6], w[7]};
    half2_t a0 = {uu[0], uu[1]}, a1 = {uu[2], uu[3]}, a2 = {uu[4], uu[5]}, a3 = {uu[6], uu[7]};
    float acc = __builtin_amdgcn_fdot2(w0, a0, 0.f, false);
    acc = __builtin_amdgcn_fdot2(w1, a1, acc, false);
    acc = __builtin_amdgcn_fdot2(w2, a2, acc, false);
    acc = __builtin_amdgcn_fdot2(w3, a3, acc, false);
    return acc;
}

struct Ctx {
    int j, chunk, bg, i0, b0, tid, il, dq, lane, w, g, xcd, local;
};

// A0m swizzle (proven): xcd owns bg == xcd, all (j,chunk)
__device__ __forceinline__ Ctx make_ctx(int bid, int tid) {
    Ctx c;
    c.xcd = bid & 7; c.local = bid >> 3;
    int gx = c.xcd * (GRID_MAIN / 8) + c.local;
    c.j = gx % NJ; int r = gx / NJ;
    c.chunk = r % NCHUNK; c.bg = r / NCHUNK;
    c.i0 = c.chunk * CHUNK; c.b0 = c.bg * BG;
    c.tid = tid; c.il = tid >> 2; c.dq = tid & 3;
    c.lane = tid & 63; c.w = tid >> 6; c.g = (c.lane >> 4) & 3;
    return c;
}

// MFMA-layout W fragment
__device__ __forceinline__ void loadWf(const _Float16* __restrict__ W16, const Ctx& cx,
                                       half8_t* Wf) {
    int drow = cx.lane & 15, ksub = cx.lane >> 4;
#pragma unroll
    for (int qq = 0; qq < 4; ++qq) {
        int i = cx.i0 + cx.w * 16 + qq * 4 + ksub;
        Wf[qq] = *(const half8_t*)(W16 + (((size_t)cx.j * NI + i) * DJ + drow) * DI);
    }
}

// ---- f32 -> f16 conversion, 4 float4 per thread (grid 936) ----
__global__ __launch_bounds__(256) void k_cvt(const float* __restrict__ uf,
                                             const float* __restrict__ Wf,
                                             _Float16* __restrict__ u16,
                                             _Float16* __restrict__ W16) {
    const int nu4 = (BB * NI * DI) / 4;
    int base = (blockIdx.x * 256 + threadIdx.x) * 4;
    if (base < nu4) {
#pragma unroll
        for (int t = 0; t < 4; ++t) {
            float4 v = ((const float4*)uf)[base + t];
            half4_t h = {(_Float16)v.x, (_Float16)v.y, (_Float16)v.z, (_Float16)v.w};
            ((half4_t*)u16)[base + t] = h;
        }
    } else {
        int k = base - nu4;
#pragma unroll
        for (int t = 0; t < 4; ++t) {
            float4 v = ((const float4*)Wf)[k + t];
            half4_t h = {(_Float16)v.x, (_Float16)v.y, (_Float16)v.z, (_Float16)v.w};
            ((half4_t*)W16)[k + t] = h;
        }
    }
}

// ---- k_A0m: iter-0 A phase, MFMA, c=0.1 exact; split accumulators ----
__global__ __launch_bounds__(256) void k_A0m(const _Float16* __restrict__ u16,
                                             const _Float16* __restrict__ W16,
                                             float* __restrict__ spart) {
    __shared__ __align__(16) float sres2[2 * 4 * 16 * 17];
    Ctx cx = make_ctx(blockIdx.x, threadIdx.x);
    half8_t Wf[4];
    loadWf(W16, cx, Wf);
    int l = cx.lane, w = cx.w;
    int drow = l & 15, ksub = l >> 4;

    half8_t au[2][4];
#pragma unroll
    for (int h = 0; h < 2; ++h) {
        int b = cx.b0 + h * 16 + drow;
#pragma unroll
        for (int qq = 0; qq < 4; ++qq) {
            int il = w * 16 + qq * 4 + ksub;
            au[h][qq] = *(const half8_t*)(u16 + ((size_t)b * NI + cx.i0 + il) * DI);
        }
    }
#pragma unroll
    for (int h = 0; h < 2; ++h) {
        f32x4 acc0 = {0.f, 0.f, 0.f, 0.f};
        f32x4 acc1 = {0.f, 0.f, 0.f, 0.f};
        acc0 = __builtin_amdgcn_mfma_f32_16x16x32_f16(au[h][0], Wf[0], acc0, 0, 0, 0);
        acc1 = __builtin_amdgcn_mfma_f32_16x16x32_f16(au[h][1], Wf[1], acc1, 0, 0, 0);
        acc0 = __builtin_amdgcn_mfma_f32_16x16x32_f16(au[h][2], Wf[2], acc0, 0, 0, 0);
        acc1 = __builtin_amdgcn_mfma_f32_16x16x32_f16(au[h][3], Wf[3], acc1, 0, 0, 0);
        f32x4 acc = acc0 + acc1;
#pragma unroll
        for (int r = 0; r < 4; ++r)
            sres2[((h * 4 + w) * 16 + ksub * 4 + r) * 17 + drow] = acc[r];
    }
    __syncthreads();
#pragma unroll
    for (int p = 0; p < 2; ++p) {
        int idx = p * 256 + cx.tid;
        int d = idx & 15, brow = (idx >> 4) & 15, h = idx >> 8;
        float s = 0.f;
#pragma unroll
        for (int w2 = 0; w2 < 4; ++w2)
            s += sres2[((h * 4 + w2) * 16 + brow) * 17 + d];
        s *= 0.1f;
        spart[(((size_t)cx.chunk * BB + cx.b0 + h * 16 + brow) * NJ + cx.j) * DJ + d] = s;
    }
}

// ---- k_BSA: fused {squash -> B -> softmax -> A} for all 10 j; BG2=8,
// 256 threads (round-23 shape — the measured optimum). PING-PONG spart:
// reads sin, writes sout (fixes the cross-block WAR race of rounds 18-24).
// ITER=0: v = v1; chunk==0 blocks persist v1 to vbuf.
// ITER=1: v = v1 + vbuf (= v0+v1): B phase produces TOTAL delta in LDS.
// Depth-2 W prefetch both j-loops; phase-4 MFMA uses split accumulators.
template <int ITER>
__global__ __launch_bounds__(256) void k_BSA(const _Float16* __restrict__ u16,
                                             const _Float16* __restrict__ W16,
                                             const float* __restrict__ sin,
                                             float* __restrict__ sout,
                                             float* __restrict__ vbuf) {
    __shared__ __align__(16) float     vsm[BG2 * NJ * DJ];        // 5120 B
    __shared__ __align__(16) _Float16  dtile[BG2 * NJ * CHUNK];   // 10240 B
    __shared__ __align__(16) _Float16  ctile[NJ * BG2 * CTP2];    // 10880 B
    __shared__ __align__(16) float     sres[NJ * 4 * BG2 * 17];   // 21760 B

    int xcd = blockIdx.x & 7, local = blockIdx.x >> 3;   // local 0..71
    int chunk = local % NCHUNK;
    int bgl   = local / NCHUNK;                          // 0..3
    int b0 = xcd * 32 + bgl * BG2;
    int i0 = chunk * CHUNK;
    int tid = threadIdx.x;
    int lane = tid & 63, w = tid >> 6;
    int il = tid >> 2, dq = tid & 3;
    int drow = lane & 15, ksub = lane >> 4;
    bool brow_ok = drow < BG2;

    // ---- early u-loads (latency hides under squash) ----
    half8_t pu[BG2];                                     // phase-2 layout
#pragma unroll
    for (int b8 = 0; b8 < BG2; ++b8)
        pu[b8] = *(const half8_t*)(u16 + ((size_t)(b0 + b8) * NI + i0 + il) * DI);
    half8_t au0[4];                                      // phase-4 layout
#pragma unroll
    for (int qq = 0; qq < 4; ++qq) {
        int ili = w * 16 + qq * 4 + ksub;
        au0[qq] = brow_ok
            ? *(const half8_t*)(u16 + ((size_t)(b0 + drow) * NI + i0 + ili) * DI)
            : (half8_t){0, 0, 0, 0, 0, 0, 0, 0};
    }
    // pre-issue phase-2 W fragments for j=0,1 (hide under phase 1)
    half8_t Wh[3][4];
#pragma unroll
    for (int jj = 0; jj < 2; ++jj) {
        const half8_t* wp = (const half8_t*)(W16 +
            (((size_t)jj * NI + i0 + il) * DJ + dq * 4) * DI);
#pragma unroll
        for (int q = 0; q < 4; ++q) Wh[jj][q] = wp[q];
    }

    // ---- phase 1: v1 = squash(sum_ch sin); vtot per ITER; 320 slots ----
#pragma unroll
    for (int p = 0; p < 2; ++p) {
        int slot = p * 256 + tid;
        if (slot < BG2 * NJ * 4) {                       // 320 (40 per b8; 40%4==0)
            int b8 = slot / 40, rem = slot - b8 * 40;
            int j = rem >> 2, dq2 = rem & 3;
            int b = b0 + b8;
            float4 s4 = {0.f, 0.f, 0.f, 0.f};
#pragma unroll
            for (int ch = 0; ch < NCHUNK; ++ch) {
                float4 t = *(const float4*)&sin[(((size_t)ch * BB + b) * NJ + j) * DJ + dq2 * 4];
                s4.x += t.x; s4.y += t.y; s4.z += t.z; s4.w += t.w;
            }
            float sq = s4.x * s4.x + s4.y * s4.y + s4.z * s4.z + s4.w * s4.w;
            sq = dpp_add<0x0B1>(sq);   // quads align with dq2
            sq = dpp_add<0x04E>(sq);
            float scale = (sq / (1.f + sq)) / sqrtf(sq + 1e-7f);
            float4 vv; vv.x = s4.x * scale; vv.y = s4.y * scale;
            vv.z = s4.z * scale; vv.w = s4.w * scale;
            size_t va = ((size_t)b * NJ + j) * DJ + dq2 * 4;
            if (ITER == 0) {
                if (chunk == 0) *(float4*)&vbuf[va] = vv;   // persist v0
            } else {
                float4 v0 = *(const float4*)&vbuf[va];      // vtot = v0 + v1
                vv.x += v0.x; vv.y += v0.y; vv.z += v0.z; vv.w += v0.w;
            }
            *(float4*)&vsm[(b8 * NJ + j) * DJ + dq2 * 4] = vv;
        }
    }
    __syncthreads();

    // ---- phase 2: B for each j (vtot . uhat) -> dtile; depth-2 prefetch ----
#pragma unroll
    for (int j = 0; j < NJ; ++j) {
        if (j + 2 < NJ) {
            const half8_t* wp = (const half8_t*)(W16 +
                (((size_t)(j + 2) * NI + i0 + il) * DJ + dq * 4) * DI);
#pragma unroll
            for (int q = 0; q < 4; ++q) Wh[(j + 2) % 3][q] = wp[q];
        }
        float pj[BG2];
#pragma unroll
        for (int b8 = 0; b8 < BG2; ++b8) {
            float4 vv = *(const float4*)&vsm[(b8 * NJ + j) * DJ + dq * 4];
            float p = vv.x * dot16(Wh[j % 3][0], pu[b8]);
            p = fmaf(vv.y, dot16(Wh[j % 3][1], pu[b8]), p);
            p = fmaf(vv.z, dot16(Wh[j % 3][2], pu[b8]), p);
            p = fmaf(vv.w, dot16(Wh[j % 3][3], pu[b8]), p);
            p = dpp_add<0x0B1>(p);
            p = dpp_add<0x04E>(p);
            pj[b8] = p;
        }
        if (dq == 0) {
#pragma unroll
            for (int b8 = 0; b8 < BG2; ++b8)
                dtile[(b8 * NJ + j) * CHUNK + il] = (_Float16)pj[b8];
        }
    }

    // pre-issue phase-4 W fragments for j=0,1 (hide under barrier + softmax)
    half8_t Wf[3][4];
#pragma unroll
    for (int jj = 0; jj < 2; ++jj) {
#pragma unroll
        for (int qq = 0; qq < 4; ++qq) {
            int i = i0 + w * 16 + qq * 4 + ksub;
            Wf[jj][qq] = *(const half8_t*)(W16 + (((size_t)jj * NI + i) * DJ + drow) * DI);
        }
    }
    __syncthreads();

    // ---- phase 3: softmax over j from dtile -> ctile (f16; no max-sub,
    //      |delta| <= ~12 analytically: f32-exp safe); 512 pairs ----
#pragma unroll
    for (int p = 0; p < 2; ++p) {
        int pair = p * 256 + tid;                        // 0..511
        int b8 = pair >> 6, i = pair & 63;
        float x[NJ]; float ssum = 0.f;
#pragma unroll
        for (int j = 0; j < NJ; ++j) {
            x[j] = __expf((float)dtile[(b8 * NJ + j) * CHUNK + i]);
            ssum += x[j];
        }
        float rs = 1.f / ssum;
#pragma unroll
        for (int j = 0; j < NJ; ++j)
            ctile[(j * BG2 + b8) * CTP2 + i] = (_Float16)(x[j] * rs);
    }
    __syncthreads();

    // ---- phase 4: MFMA A per j (rows BG2..15 idle); depth-2 prefetch;
    //      split accumulators (two independent 2-deep MFMA chains) ----
#pragma unroll
    for (int j = 0; j < NJ; ++j) {
        if (j + 2 < NJ) {
#pragma unroll
            for (int qq = 0; qq < 4; ++qq) {
                int i = i0 + w * 16 + qq * 4 + ksub;
                Wf[(j + 2) % 3][qq] =
                    *(const half8_t*)(W16 + (((size_t)(j + 2) * NI + i) * DJ + drow) * DI);
            }
        }
        half8_t av[4];
#pragma unroll
        for (int qq = 0; qq < 4; ++qq) {
            int ili = w * 16 + qq * 4 + ksub;
            _Float16 ch = brow_ok ? ctile[(j * BG2 + drow) * CTP2 + ili] : (_Float16)0.f;
            half8_t cc = {ch, ch, ch, ch, ch, ch, ch, ch};
            av[qq] = au0[qq] * cc;
        }
        f32x4 acc0 = {0.f, 0.f, 0.f, 0.f};
        f32x4 acc1 = {0.f, 0.f, 0.f, 0.f};
        acc0 = __builtin_amdgcn_mfma_f32_16x16x32_f16(av[0], Wf[j % 3][0], acc0, 0, 0, 0);
        acc1 = __builtin_amdgcn_mfma_f32_16x16x32_f16(av[1], Wf[j % 3][1], acc1, 0, 0, 0);
        acc0 = __builtin_amdgcn_mfma_f32_16x16x32_f16(av[2], Wf[j % 3][2], acc0, 0, 0, 0);
        acc1 = __builtin_amdgcn_mfma_f32_16x16x32_f16(av[3], Wf[j % 3][3], acc1, 0, 0, 0);
        f32x4 acc = acc0 + acc1;
        if (ksub < 2) {                                  // output rows 0..7
#pragma unroll
            for (int r = 0; r < 4; ++r)
                sres[((j * 4 + w) * BG2 + ksub * 4 + r) * 17 + drow] = acc[r];
        }
    }
    __syncthreads();
    // epilogue: 1280 outputs (j 10 x brow 8 x d 16), 5 passes
#pragma unroll
    for (int p = 0; p < 5; ++p) {
        int idx = p * 256 + tid;                         // 0..1279
        int d = idx & 15, brow2 = (idx >> 4) & 7, j = idx >> 7;
        float s = 0.f;
#pragma unroll
        for (int w2 = 0; w2 < 4; ++w2)
            s += sres[((j * 4 + w2) * BG2 + brow2) * 17 + d];
        sout[(((size_t)chunk * BB + b0 + brow2) * NJ + j) * DJ + d] = s;
    }
}

// ---- k_V: out = squash(sum_ch spart), vectorized: 40 blocks x 256 ----
__global__ __launch_bounds__(256) void k_V(const float* __restrict__ spart,
                                           float* __restrict__ out) {
    int idx4 = blockIdx.x * 256 + threadIdx.x;
    float4 s4 = {0.f, 0.f, 0.f, 0.f};
#pragma unroll
    for (int ch = 0; ch < NCHUNK; ++ch) {
        float4 t = *(const float4*)&spart[(size_t)ch * (BB * NJ * DJ) + (size_t)idx4 * 4];
        s4.x += t.x; s4.y += t.y; s4.z += t.z; s4.w += t.w;
    }
    float sq = s4.x * s4.x + s4.y * s4.y + s4.z * s4.z + s4.w * s4.w;
    sq = dpp_add<0x0B1>(sq);
    sq = dpp_add<0x04E>(sq);
    float scale = (sq / (1.f + sq)) / sqrtf(sq + 1e-7f);
    float4 o; o.x = s4.x * scale; o.y = s4.y * scale;
    o.z = s4.z * scale; o.w = s4.w * scale;
    *(float4*)&out[(size_t)idx4 * 4] = o;
}

extern "C" void kernel_launch(void* const* d_in, const int* in_sizes, int n_in,
                              void* d_out, int out_size, void* d_ws, size_t ws_size,
                              hipStream_t stream) {
    const float* u = (const float*)d_in[0];   // (256,1152,8)
    const float* W = (const float*)d_in[1];   // (10,1152,16,8)
    float* out = (float*)d_out;               // (256,10,16)

    const size_t SPART_N = (size_t)NCHUNK * BB * NJ * DJ;         // 737280
    float*     spartA = (float*)d_ws;
    float*     spartB = spartA + SPART_N;
    float*     vbuf   = spartB + SPART_N;                         // BB*NJ*DJ f32
    _Float16*  u16    = (_Float16*)(vbuf + (size_t)BB * NJ * DJ);
    _Float16*  W16    = u16 + (size_t)BB * NI * DI;

    dim3 blk(256);
    const int GRID_CVT = ((BB * NI * DI) / 4 + (NJ * NI * DJ * DI) / 4) / (256 * 4);  // 936

    // 5 launches: cvt -> A0m(A) -> BSA0(A->B) -> BSA1(B->A) -> V(A)
    k_cvt<<<GRID_CVT, blk, 0, stream>>>(u, W, u16, W16);
    k_A0m<<<GRID_MAIN, blk, 0, stream>>>(u16, W16, spartA);
    k_BSA<0><<<GRID_BSA, blk, 0, stream>>>(u16, W16, spartA, spartB, vbuf);
    k_BSA<1><<<GRID_BSA, blk, 0, stream>>>(u16, W16, spartB, spartA, vbuf);
    k_V<<<40, blk, 0, stream>>>(spartA, out);
}